// Round 3
// baseline (238.116 us; speedup 1.0000x reference)
//
#include <hip/hip_runtime.h>
#include <hip/hip_bf16.h>
#include <math.h>

#define DEV static __device__ __forceinline__

typedef float f32x4 __attribute__((ext_vector_type(4)));
typedef short s16x8 __attribute__((ext_vector_type(8)));
typedef unsigned short u16;
typedef unsigned int u32;
typedef u32 u32x2 __attribute__((ext_vector_type(2)));
typedef u16 u16x4 __attribute__((ext_vector_type(4)));
typedef u16 u16x8 __attribute__((ext_vector_type(8)));

#define SSCALE 0.35355339059327379f   // 64^-0.25

DEV f32x4 mfma16(s16x8 a, s16x8 b, f32x4 c) {
  return __builtin_amdgcn_mfma_f32_16x16x32_bf16(a, b, c, 0, 0, 0);
}

DEV float bf2f(u16 x) { u32 u = ((u32)x) << 16; float f; __builtin_memcpy(&f, &u, 4); return f; }
DEV u16 f2bf(float x) { __hip_bfloat16 b = __float2bfloat16(x); u16 r; __builtin_memcpy(&r, &b, 2); return r; }

DEV void gload_lds16(const void* g, void* l) {
  __builtin_amdgcn_global_load_lds((const __attribute__((address_space(1))) u32*)g,
                                   (__attribute__((address_space(3))) u32*)l, 16, 0, 0);
}

// ---------------------------------------------------------------------------
// prep (multi-mode by block range):
//   [0,2048)    x0|x1 -> Xb bf16 (vectorized)
//   [2048,2144) 96 LDS-tiled 64x64 transposes: Wqk^T,Wv^T -> btqkv;
//               W1a^T -> btF[:, :256]; W2^T -> bt2
//   [2144,2656) Wc = Wo @ W1b (f32 accum) -> btF[:, 256:]   (Wo-GEMM fusion)
//   [2656,2658) bc = b1 + bo @ W1b (f32)
// ---------------------------------------------------------------------------
__global__ __launch_bounds__(256) void k_prep(
    const float* __restrict__ x0, const float* __restrict__ x1,
    const float* __restrict__ Wqk, const float* __restrict__ Wv,
    const float* __restrict__ Wo, const float* __restrict__ W1,
    const float* __restrict__ W2, const float* __restrict__ bo,
    const float* __restrict__ b1,
    u16* __restrict__ btqkv, u16* __restrict__ btF,
    u16* __restrict__ bt2, float* __restrict__ bc, u16* __restrict__ Xb)
{
  const int blk = blockIdx.x, tid = threadIdx.x;
  if (blk < 2048) {               // x convert: 2048 elems per block
    int idx = blk * 2048 + tid * 8;
    const float* src = (idx < 2097152) ? (x0 + idx) : (x1 + (idx - 2097152));
    f32x4 va = *(const f32x4*)src;
    f32x4 vb = *(const f32x4*)(src + 4);
    u16x8 o;
#pragma unroll
    for (int j = 0; j < 4; ++j) { o[j] = f2bf(va[j]); o[4 + j] = f2bf(vb[j]); }
    *(u16x8*)(Xb + idx) = o;
  } else if (blk < 2144) {        // transpose tiles
    __shared__ float T[64][65];
    int tb = blk - 2048;
    const float* src; u16* dst; int sld, dld, kr0, c0, drow0;
    if (tb < 16)      { src = Wqk; dst = btqkv; sld = 256; dld = 256; drow0 = 0;
                        kr0 = (tb >> 2) * 64; c0 = (tb & 3) * 64; }
    else if (tb < 32) { tb -= 16; src = Wv; dst = btqkv; sld = 256; dld = 256; drow0 = 256;
                        kr0 = (tb >> 2) * 64; c0 = (tb & 3) * 64; }
    else if (tb < 64) { tb -= 32; src = W1; dst = btF; sld = 512; dld = 512; drow0 = 0;
                        kr0 = (tb >> 3) * 64; c0 = (tb & 7) * 64; }
    else              { tb -= 64; src = W2; dst = bt2; sld = 256; dld = 512; drow0 = 0;
                        kr0 = (tb >> 2) * 64; c0 = (tb & 3) * 64; }
    int r = tid >> 2, cq = (tid & 3) * 16;
#pragma unroll
    for (int q = 0; q < 4; ++q) {
      f32x4 v = *(const f32x4*)(src + (size_t)(kr0 + r) * sld + c0 + cq + q * 4);
#pragma unroll
      for (int e = 0; e < 4; ++e) T[r][cq + q * 4 + e] = v[e];
    }
    __syncthreads();
    int c = tid >> 2, kq = (tid & 3) * 16;
#pragma unroll
    for (int q = 0; q < 2; ++q) {
      u16x8 o;
#pragma unroll
      for (int e = 0; e < 8; ++e) o[e] = f2bf(T[kq + q * 8 + e][c]);
      *(u16x8*)(dst + (size_t)(drow0 + c0 + c) * dld + kr0 + kq + q * 8) = o;
    }
  } else if (blk < 2656) {        // Wc^T[n][i] = sum_j W1[(256+j)][n] * Wo[i][j]
    int wb = blk - 2144;
    int i = wb >> 1;
    int n = (wb & 1) * 256 + tid;
    float a0 = 0.f, a1 = 0.f, a2 = 0.f, a3 = 0.f;
    for (int j = 0; j < 256; j += 4) {
      a0 = fmaf(Wo[i * 256 + j],     W1[(size_t)(256 + j) * 512 + n], a0);
      a1 = fmaf(Wo[i * 256 + j + 1], W1[(size_t)(257 + j) * 512 + n], a1);
      a2 = fmaf(Wo[i * 256 + j + 2], W1[(size_t)(258 + j) * 512 + n], a2);
      a3 = fmaf(Wo[i * 256 + j + 3], W1[(size_t)(259 + j) * 512 + n], a3);
    }
    btF[(size_t)n * 512 + 256 + i] = f2bf((a0 + a1) + (a2 + a3));
  } else {                        // bc[n] = b1[n] + sum_j bo[j]*W1[(256+j)][n]
    int n = (blk - 2656) * 256 + tid;
    float acc = b1[n];
    for (int j = 0; j < 256; ++j)
      acc = fmaf(bo[j], W1[(size_t)(256 + j) * 512 + n], acc);
    bc[n] = acc;
  }
}

// ---------------------------------------------------------------------------
// GEMM: C[16384 x Ncols] = A(bf16,[M][KD], split A1|A2 at K1) @ Bt^T
// Bt is [Ncols][KD] bf16. 128xBN tile, 4 waves, BK=32, double-buffered
// global_load_lds, XOR-swizzled LDS.
// EPI 0: qk/vt scatter (+bias,*SS / +bias, packed-n stores)
// EPI 1: bf16 out (+bias)      EPI 3: f32 out (+bias +residual x)
// ---------------------------------------------------------------------------
template <int KD, int K1, int EPI, int BN>
__global__ __launch_bounds__(256, 2) void k_gemm(
    const u16* __restrict__ A1, const u16* __restrict__ A2,
    const u16* __restrict__ Bt,
    const float* __restrict__ bias, const float* __restrict__ bias2,
    const float* __restrict__ res0, const float* __restrict__ res1,
    u16* __restrict__ outb, u16* __restrict__ outb2,
    float* __restrict__ outf, int Ncols)
{
  constexpr int MR = (BN == 128) ? 4 : 2;       // row-tiles per wave
  __shared__ char lds[16384 + 2 * BN * 64];
  char* ldsA = lds;
  char* ldsB = lds + 16384;
  const int tid = threadIdx.x;
  const int lane = tid & 63;
  const int w = tid >> 6;
  const int wm = (BN == 128) ? (w >> 1) : w;
  const int wn = (BN == 128) ? (w & 1) : 0;
  const int g = lane >> 4, li = lane & 15;
  const int m0 = blockIdx.x * 128, n0 = blockIdx.y * BN;

  auto stage = [&](int buf, int t) {
    const int k0 = t * 32;
#pragma unroll
    for (int it = 0; it < 2; ++it) {
      int chunk = it * 256 + w * 64 + lane;
      int row = chunk >> 2, c = chunk & 3;
      int kc = k0 + ((c ^ ((row >> 1) & 3)) << 3);
      const u16* src = (kc < K1) ? (A1 + (size_t)(m0 + row) * K1 + kc)
                                 : (A2 + (size_t)(m0 + row) * (KD - K1) + (kc - K1));
      gload_lds16(src, ldsA + buf * 8192 + (it * 256 + w * 64) * 16);
    }
#pragma unroll
    for (int it = 0; it < BN / 64; ++it) {
      int chunk = it * 256 + w * 64 + lane;
      int row = chunk >> 2, c = chunk & 3;
      int kc = k0 + ((c ^ ((row >> 1) & 3)) << 3);
      gload_lds16(Bt + (size_t)(n0 + row) * KD + kc,
                  ldsB + buf * (BN * 64) + (it * 256 + w * 64) * 16);
    }
  };

  f32x4 acc[MR][4] = {};

  stage(0, 0);
  __syncthreads();
  const int NT = KD / 32;
  for (int t = 0; t < NT; ++t) {
    if (t + 1 < NT) stage((t + 1) & 1, t + 1);
    const char* bufA = ldsA + (t & 1) * 8192;
    const char* bufB = ldsB + (t & 1) * (BN * 64);
    s16x8 af[MR], bfr[4];
#pragma unroll
    for (int rt = 0; rt < MR; ++rt) {
      int row = wm * (MR * 16) + rt * 16 + li;
      af[rt] = *(const s16x8*)(bufA + row * 64 + ((g ^ ((row >> 1) & 3)) << 4));
    }
#pragma unroll
    for (int ct = 0; ct < 4; ++ct) {
      int col = wn * 64 + ct * 16 + li;
      bfr[ct] = *(const s16x8*)(bufB + col * 64 + ((g ^ ((col >> 1) & 3)) << 4));
    }
#pragma unroll
    for (int rt = 0; rt < MR; ++rt)
#pragma unroll
      for (int ct = 0; ct < 4; ++ct)
        acc[rt][ct] = mfma16(af[rt], bfr[ct], acc[rt][ct]);
    __syncthreads();
  }

#pragma unroll
  for (int rt = 0; rt < MR; ++rt) {
#pragma unroll
    for (int ct = 0; ct < 4; ++ct) {
      const int growb = m0 + wm * (MR * 16) + rt * 16 + g * 4;   // base row (r=0)
      const int gcol = n0 + wn * 64 + ct * 16 + li;
      if (EPI == 0) {
        const int dir = growb >> 13, bb = (growb >> 11) & 3, n = growb & 2047;
        if (gcol < 256) {
          const int h = gcol >> 6, dh = gcol & 63;
#pragma unroll
          for (int r = 0; r < 4; ++r) {
            float q = (acc[rt][ct][r] + bias[gcol]) * SSCALE;
            outb[((size_t)(dir * 16 + bb * 4 + h) * 2048 + (n + r)) * 64 + dh] = f2bf(q);
          }
        } else {
          const int c2 = gcol - 256, h = c2 >> 6, dh = c2 & 63;
          u16x4 pk;
#pragma unroll
          for (int r = 0; r < 4; ++r) pk[r] = f2bf(acc[rt][ct][r] + bias2[c2]);
          *(u16x4*)(outb2 + ((size_t)(dir * 16 + bb * 4 + h) * 64 + dh) * 2048 + n) = pk;
        }
      } else if (EPI == 1) {
#pragma unroll
        for (int r = 0; r < 4; ++r)
          outb[(size_t)(growb + r) * Ncols + gcol] = f2bf(acc[rt][ct][r] + bias[gcol]);
      } else {
#pragma unroll
        for (int r = 0; r < 4; ++r) {
          int grow = growb + r;
          float x = (grow < 8192) ? res0[(size_t)grow * 256 + gcol]
                                  : res1[(size_t)(grow - 8192) * 256 + gcol];
          outf[(size_t)grow * 256 + gcol] = acc[rt][ct][r] + bias[gcol] + x;
        }
      }
    }
  }
}

// ---------------------------------------------------------------------------
// attention: 32 problems (dir,bh) x 32 q-tiles of 64 rows. 4 waves x 16 q-rows.
// LDS 40KB -> 4 blocks/CU; grid 1024 = exactly 4/CU. XCD-chunked swizzle so
// each XCD's blocks share a 2MB KV working set in its L2.
// Transposed-S mfma(K,Q); logits tiny -> softmax without max subtraction;
// normalize in-kernel, write bf16 m_all directly.
// ---------------------------------------------------------------------------
__global__ __launch_bounds__(256, 4) void k_attn(
    const u16* __restrict__ qk, const u16* __restrict__ vt, u16* __restrict__ m_all)
{
  __shared__ char Kl[2][8192];
  __shared__ char Vl[2][8192];
  __shared__ char Pl[4][2048];
  const int tid = threadIdx.x, lane = tid & 63, w = tid >> 6;
  const int g = lane >> 4, li = lane & 15;
  const int sw = (blockIdx.x & 7) * 128 + (blockIdx.x >> 3);  // XCD chunking
  const int qblk = sw & 31;
  const int p = sw >> 5;
  const int dir = p >> 4, bh = p & 15;
  const char* Qg = (const char*)qk + (size_t)p * 262144;
  const char* Kg = (const char*)qk + (size_t)((dir ^ 1) * 16 + bh) * 262144;
  const char* Vg = (const char*)vt + (size_t)((dir ^ 1) * 16 + bh) * 262144;
  const int q0 = qblk * 64 + w * 16;

  // Q fragments in registers (reused across the whole j loop)
  s16x8 qf0 = *(const s16x8*)(Qg + (size_t)(q0 + li) * 128 + g * 16);
  s16x8 qf1 = *(const s16x8*)(Qg + (size_t)(q0 + li) * 128 + 64 + g * 16);

  auto stageKV = [&](int buf, int jt) {
#pragma unroll
    for (int it = 0; it < 2; ++it) {
      int chunk = it * 256 + w * 64 + lane;
      int row = chunk >> 3, c = chunk & 7;
      int cc = (c ^ (row & 7)) << 4;
      gload_lds16(Kg + (size_t)(jt * 64 + row) * 128 + cc, &Kl[buf][(it * 256 + w * 64) * 16]);
    }
#pragma unroll
    for (int it = 0; it < 2; ++it) {
      int chunk = it * 256 + w * 64 + lane;
      int row = chunk >> 3, c = chunk & 7;
      int cc = (c ^ (row & 7)) << 4;
      gload_lds16(Vg + (size_t)row * 4096 + jt * 128 + cc, &Vl[buf][(it * 256 + w * 64) * 16]);
    }
  };

  f32x4 acco[4] = {};
  float accl = 0.f;

  stageKV(0, 0);
  __syncthreads();
  for (int jt = 0; jt < 32; ++jt) {
    if (jt + 1 < 32) stageKV((jt + 1) & 1, jt + 1);
    const char* Kb = Kl[jt & 1];
    const char* Vb = Vl[jt & 1];

    // S^T = mfma(K,Q): lane (g,li) holds keys kt*16+g*4+{0..3} of q-row li.
#pragma unroll
    for (int kt = 0; kt < 4; ++kt) {
      const int krow = kt * 16 + li;
      s16x8 kf0 = *(const s16x8*)(Kb + krow * 128 + ((g ^ (li & 7)) << 4));
      s16x8 kf1 = *(const s16x8*)(Kb + krow * 128 + (((4 + g) ^ (li & 7)) << 4));
      f32x4 s = {0.f, 0.f, 0.f, 0.f};
      s = mfma16(kf0, qf0, s);
      s = mfma16(kf1, qf1, s);
      float p0 = __expf(s[0]), p1 = __expf(s[1]);
      float p2 = __expf(s[2]), p3 = __expf(s[3]);
      accl += (p0 + p1) + (p2 + p3);
      u32x2 pk;
      pk.x = (u32)f2bf(p0) | ((u32)f2bf(p1) << 16);
      pk.y = (u32)f2bf(p2) | ((u32)f2bf(p3) << 16);
      *(u32x2*)(&Pl[w][(li * 128 + kt * 32 + g * 8) ^ ((li & 7) << 4)]) = pk;
    }

    // O += P V (same-wave LDS round trip; compiler orders via lgkmcnt)
#pragma unroll
    for (int ks = 0; ks < 2; ++ks) {
      s16x8 pf = *(const s16x8*)(&Pl[w][(li * 128 + ks * 64 + g * 16) ^ ((li & 7) << 4)]);
#pragma unroll
      for (int dt = 0; dt < 4; ++dt) {
        const int vrow = dt * 16 + li;
        s16x8 vfr = *(const s16x8*)(Vb + vrow * 128 + (((ks * 4 + g) ^ (li & 7)) << 4));
        acco[dt] = mfma16(pf, vfr, acco[dt]);
      }
    }
    __syncthreads();
  }

  // row sums live per (g,li) for q-row li: reduce across g, then fetch the
  // inverse for the q-rows (g*4+r) this lane's accumulator holds.
  accl += __shfl_xor(accl, 16);
  accl += __shfl_xor(accl, 32);
  float inv = 1.0f / accl;
  float invq[4];
#pragma unroll
  for (int r = 0; r < 4; ++r) invq[r] = __shfl(inv, g * 4 + r);

  const int bb = bh >> 2, h = bh & 3;
  const size_t rowb = (size_t)dir * 8192 + (size_t)bb * 2048 + q0 + g * 4;
#pragma unroll
  for (int dt = 0; dt < 4; ++dt)
#pragma unroll
    for (int r = 0; r < 4; ++r)
      m_all[(rowb + r) * 256 + h * 64 + dt * 16 + li] = f2bf(acco[dt][r] * invq[r]);
}

// ---------------------------------------------------------------------------
// layernorm (over 512) + exact gelu; one wave per row
// ---------------------------------------------------------------------------
__global__ __launch_bounds__(256) void k_ln_gelu(
    const u16* __restrict__ h, const float* __restrict__ lg,
    const float* __restrict__ lb, u16* __restrict__ o)
{
  int lane = threadIdx.x & 63;
  size_t row = blockIdx.x * 4 + (threadIdx.x >> 6);
  s16x8 v = *(const s16x8*)(h + row * 512 + lane * 8);
  float f[8], s = 0.f, s2 = 0.f;
#pragma unroll
  for (int j = 0; j < 8; ++j) { f[j] = bf2f((u16)v[j]); s += f[j]; s2 += f[j] * f[j]; }
#pragma unroll
  for (int m = 1; m < 64; m <<= 1) { s += __shfl_xor(s, m); s2 += __shfl_xor(s2, m); }
  float mu = s * (1.0f / 512.0f);
  float var = s2 * (1.0f / 512.0f) - mu * mu;
  float rs = rsqrtf(var + 1e-5f);
  s16x8 ov;
#pragma unroll
  for (int j = 0; j < 8; ++j) {
    int c = lane * 8 + j;
    float y = (f[j] - mu) * rs * lg[c] + lb[c];
    float ge = 0.5f * y * (1.0f + erff(y * 0.70710678118654752f));
    ov[j] = (short)f2bf(ge);
  }
  *(s16x8*)(o + row * 512 + lane * 8) = ov;
}

// ---------------------------------------------------------------------------
extern "C" void kernel_launch(void* const* d_in, const int* in_sizes, int n_in,
                              void* d_out, int out_size, void* d_ws, size_t ws_size,
                              hipStream_t stream)
{
  const float* x0  = (const float*)d_in[0];
  const float* x1  = (const float*)d_in[1];
  const float* Wqk = (const float*)d_in[2];
  const float* bqk = (const float*)d_in[3];
  const float* Wv  = (const float*)d_in[4];
  const float* bv  = (const float*)d_in[5];
  const float* Wo  = (const float*)d_in[6];
  const float* bo  = (const float*)d_in[7];
  const float* W1  = (const float*)d_in[8];
  const float* b1  = (const float*)d_in[9];
  const float* lg  = (const float*)d_in[10];
  const float* lb  = (const float*)d_in[11];
  const float* W2  = (const float*)d_in[12];
  const float* b2  = (const float*)d_in[13];
  float* out = (float*)d_out;
  char* ws = (char*)d_ws;

  u16*   Xb    = (u16*)(ws + 0);          // 16384x256 bf16
  u16*   qk    = (u16*)(ws + 8388608);    // [2][4][4][2048][64] bf16 (scaled)
  u16*   vt    = (u16*)(ws + 16777216);   // [2][4][4][64][2048] bf16 (V^T)
  u16*   m_all = (u16*)(ws + 25165824);   // 16384x256 bf16 (normalized attn out)
  u16*   hpre  = (u16*)(ws + 33554432);   // 16384x512 bf16
  u16*   gact  = (u16*)(ws + 50331648);   // 16384x512 bf16
  u16*   btqkv = (u16*)(ws + 67108864);   // [512][256]
  u16*   btF   = (u16*)(ws + 67371008);   // [512][512]: [:, :256]=W1a^T, [:, 256:]=Wc^T
  u16*   bt2   = (u16*)(ws + 67895296);   // [256][512]
  float* bc    = (float*)(ws + 68419584); // [512] fused FFN1 bias

  k_prep<<<dim3(2658), dim3(256), 0, stream>>>(x0, x1, Wqk, Wv, Wo, W1, W2, bo, b1,
                                               btqkv, btF, bt2, bc, Xb);
  k_gemm<256, 256, 0, 128><<<dim3(128, 4), dim3(256), 0, stream>>>(
      Xb, nullptr, btqkv, bqk, bv, nullptr, nullptr, qk, vt, nullptr, 512);
  k_attn<<<dim3(1024), dim3(256), 0, stream>>>(qk, vt, m_all);
  k_gemm<512, 256, 1, 128><<<dim3(128, 4), dim3(256), 0, stream>>>(
      Xb, m_all, btF, bc, nullptr, nullptr, nullptr, hpre, nullptr, nullptr, 512);
  k_ln_gelu<<<dim3(4096), dim3(256), 0, stream>>>(hpre, lg, lb, gact);
  k_gemm<512, 512, 3, 64><<<dim3(128, 4), dim3(256), 0, stream>>>(
      gact, nullptr, bt2, b2, nullptr, x0, x1, nullptr, nullptr, out, 256);
}

// Round 4
// 230.424 us; speedup vs baseline: 1.0334x; 1.0334x over previous
//
#include <hip/hip_runtime.h>
#include <hip/hip_bf16.h>
#include <math.h>

#define DEV static __device__ __forceinline__

typedef float f32x4 __attribute__((ext_vector_type(4)));
typedef short s16x8 __attribute__((ext_vector_type(8)));
typedef unsigned short u16;
typedef unsigned int u32;
typedef u32 u32x2 __attribute__((ext_vector_type(2)));
typedef u16 u16x4 __attribute__((ext_vector_type(4)));
typedef u16 u16x8 __attribute__((ext_vector_type(8)));

#define SSCALE 0.35355339059327379f   // 64^-0.25

DEV f32x4 mfma16(s16x8 a, s16x8 b, f32x4 c) {
  return __builtin_amdgcn_mfma_f32_16x16x32_bf16(a, b, c, 0, 0, 0);
}

DEV float bf2f(u16 x) { u32 u = ((u32)x) << 16; float f; __builtin_memcpy(&f, &u, 4); return f; }
DEV u16 f2bf(float x) { __hip_bfloat16 b = __float2bfloat16(x); u16 r; __builtin_memcpy(&r, &b, 2); return r; }

DEV void gload_lds16(const void* g, void* l) {
  __builtin_amdgcn_global_load_lds((const __attribute__((address_space(1))) u32*)g,
                                   (__attribute__((address_space(3))) u32*)l, 16, 0, 0);
}

// ---------------------------------------------------------------------------
// prep (multi-mode by block range):
//   [0,2048)    x0|x1 -> Xb bf16 (vectorized)
//   [2048,2144) 96 LDS-tiled 64x64 transposes: Wqk^T,Wv^T -> btqkv;
//               W1a^T -> btF[:, :256]; W2^T -> bt2
//   [2144,2656) Wc = Wo @ W1b (f32 accum) -> btF[:, 256:]   (Wo-GEMM fusion)
//   [2656,2658) bc = b1 + bo @ W1b (f32)
// ---------------------------------------------------------------------------
__global__ __launch_bounds__(256) void k_prep(
    const float* __restrict__ x0, const float* __restrict__ x1,
    const float* __restrict__ Wqk, const float* __restrict__ Wv,
    const float* __restrict__ Wo, const float* __restrict__ W1,
    const float* __restrict__ W2, const float* __restrict__ bo,
    const float* __restrict__ b1,
    u16* __restrict__ btqkv, u16* __restrict__ btF,
    u16* __restrict__ bt2, float* __restrict__ bc, u16* __restrict__ Xb)
{
  const int blk = blockIdx.x, tid = threadIdx.x;
  if (blk < 2048) {               // x convert: 2048 elems per block
    int idx = blk * 2048 + tid * 8;
    const float* src = (idx < 2097152) ? (x0 + idx) : (x1 + (idx - 2097152));
    f32x4 va = *(const f32x4*)src;
    f32x4 vb = *(const f32x4*)(src + 4);
    u16x8 o;
#pragma unroll
    for (int j = 0; j < 4; ++j) { o[j] = f2bf(va[j]); o[4 + j] = f2bf(vb[j]); }
    *(u16x8*)(Xb + idx) = o;
  } else if (blk < 2144) {        // transpose tiles
    __shared__ float T[64][65];
    int tb = blk - 2048;
    const float* src; u16* dst; int sld, dld, kr0, c0, drow0;
    if (tb < 16)      { src = Wqk; dst = btqkv; sld = 256; dld = 256; drow0 = 0;
                        kr0 = (tb >> 2) * 64; c0 = (tb & 3) * 64; }
    else if (tb < 32) { tb -= 16; src = Wv; dst = btqkv; sld = 256; dld = 256; drow0 = 256;
                        kr0 = (tb >> 2) * 64; c0 = (tb & 3) * 64; }
    else if (tb < 64) { tb -= 32; src = W1; dst = btF; sld = 512; dld = 512; drow0 = 0;
                        kr0 = (tb >> 3) * 64; c0 = (tb & 7) * 64; }
    else              { tb -= 64; src = W2; dst = bt2; sld = 256; dld = 512; drow0 = 0;
                        kr0 = (tb >> 2) * 64; c0 = (tb & 3) * 64; }
    int r = tid >> 2, cq = (tid & 3) * 16;
#pragma unroll
    for (int q = 0; q < 4; ++q) {
      f32x4 v = *(const f32x4*)(src + (size_t)(kr0 + r) * sld + c0 + cq + q * 4);
#pragma unroll
      for (int e = 0; e < 4; ++e) T[r][cq + q * 4 + e] = v[e];
    }
    __syncthreads();
    int c = tid >> 2, kq = (tid & 3) * 16;
#pragma unroll
    for (int q = 0; q < 2; ++q) {
      u16x8 o;
#pragma unroll
      for (int e = 0; e < 8; ++e) o[e] = f2bf(T[kq + q * 8 + e][c]);
      *(u16x8*)(dst + (size_t)(drow0 + c0 + c) * dld + kr0 + kq + q * 8) = o;
    }
  } else if (blk < 2656) {        // Wc^T[n][i] = sum_j W1[(256+j)][n] * Wo[i][j]
    int wb = blk - 2144;
    int i = wb >> 1;
    int n = (wb & 1) * 256 + tid;
    float a0 = 0.f, a1 = 0.f, a2 = 0.f, a3 = 0.f;
    for (int j = 0; j < 256; j += 4) {
      a0 = fmaf(Wo[i * 256 + j],     W1[(size_t)(256 + j) * 512 + n], a0);
      a1 = fmaf(Wo[i * 256 + j + 1], W1[(size_t)(257 + j) * 512 + n], a1);
      a2 = fmaf(Wo[i * 256 + j + 2], W1[(size_t)(258 + j) * 512 + n], a2);
      a3 = fmaf(Wo[i * 256 + j + 3], W1[(size_t)(259 + j) * 512 + n], a3);
    }
    btF[(size_t)n * 512 + 256 + i] = f2bf((a0 + a1) + (a2 + a3));
  } else {                        // bc[n] = b1[n] + sum_j bo[j]*W1[(256+j)][n]
    int n = (blk - 2656) * 256 + tid;
    float acc = b1[n];
    for (int j = 0; j < 256; ++j)
      acc = fmaf(bo[j], W1[(size_t)(256 + j) * 512 + n], acc);
    bc[n] = acc;
  }
}

// ---------------------------------------------------------------------------
// GEMM: C[16384 x Ncols] = A(bf16,[M][KD], split A1|A2 at K1) @ Bt^T
// Bt is [Ncols][KD] bf16. 128xBN tile, 4 waves, BK=32, double-buffered
// global_load_lds, XOR-swizzled LDS.
// EPI 0: qk/vt scatter (+bias,*SS / +bias, packed-n stores)
// EPI 1: bf16 out (+bias)      EPI 3: f32 out (+bias +residual x)
// ---------------------------------------------------------------------------
template <int KD, int K1, int EPI, int BN>
__global__ __launch_bounds__(256, 2) void k_gemm(
    const u16* __restrict__ A1, const u16* __restrict__ A2,
    const u16* __restrict__ Bt,
    const float* __restrict__ bias, const float* __restrict__ bias2,
    const float* __restrict__ res0, const float* __restrict__ res1,
    u16* __restrict__ outb, u16* __restrict__ outb2,
    float* __restrict__ outf, int Ncols)
{
  constexpr int MR = (BN == 128) ? 4 : 2;       // row-tiles per wave
  __shared__ char lds[16384 + 2 * BN * 64];
  char* ldsA = lds;
  char* ldsB = lds + 16384;
  const int tid = threadIdx.x;
  const int lane = tid & 63;
  const int w = tid >> 6;
  const int wm = (BN == 128) ? (w >> 1) : w;
  const int wn = (BN == 128) ? (w & 1) : 0;
  const int g = lane >> 4, li = lane & 15;
  const int m0 = blockIdx.x * 128, n0 = blockIdx.y * BN;

  auto stage = [&](int buf, int t) {
    const int k0 = t * 32;
#pragma unroll
    for (int it = 0; it < 2; ++it) {
      int chunk = it * 256 + w * 64 + lane;
      int row = chunk >> 2, c = chunk & 3;
      int kc = k0 + ((c ^ ((row >> 1) & 3)) << 3);
      const u16* src = (kc < K1) ? (A1 + (size_t)(m0 + row) * K1 + kc)
                                 : (A2 + (size_t)(m0 + row) * (KD - K1) + (kc - K1));
      gload_lds16(src, ldsA + buf * 8192 + (it * 256 + w * 64) * 16);
    }
#pragma unroll
    for (int it = 0; it < BN / 64; ++it) {
      int chunk = it * 256 + w * 64 + lane;
      int row = chunk >> 2, c = chunk & 3;
      int kc = k0 + ((c ^ ((row >> 1) & 3)) << 3);
      gload_lds16(Bt + (size_t)(n0 + row) * KD + kc,
                  ldsB + buf * (BN * 64) + (it * 256 + w * 64) * 16);
    }
  };

  f32x4 acc[MR][4] = {};

  stage(0, 0);
  __syncthreads();
  const int NT = KD / 32;
  for (int t = 0; t < NT; ++t) {
    if (t + 1 < NT) stage((t + 1) & 1, t + 1);
    const char* bufA = ldsA + (t & 1) * 8192;
    const char* bufB = ldsB + (t & 1) * (BN * 64);
    s16x8 af[MR], bfr[4];
#pragma unroll
    for (int rt = 0; rt < MR; ++rt) {
      int row = wm * (MR * 16) + rt * 16 + li;
      af[rt] = *(const s16x8*)(bufA + row * 64 + ((g ^ ((row >> 1) & 3)) << 4));
    }
#pragma unroll
    for (int ct = 0; ct < 4; ++ct) {
      int col = wn * 64 + ct * 16 + li;
      bfr[ct] = *(const s16x8*)(bufB + col * 64 + ((g ^ ((col >> 1) & 3)) << 4));
    }
#pragma unroll
    for (int rt = 0; rt < MR; ++rt)
#pragma unroll
      for (int ct = 0; ct < 4; ++ct)
        acc[rt][ct] = mfma16(af[rt], bfr[ct], acc[rt][ct]);
    __syncthreads();
  }

#pragma unroll
  for (int rt = 0; rt < MR; ++rt) {
#pragma unroll
    for (int ct = 0; ct < 4; ++ct) {
      const int growb = m0 + wm * (MR * 16) + rt * 16 + g * 4;   // base row (r=0)
      const int gcol = n0 + wn * 64 + ct * 16 + li;
      if (EPI == 0) {
        const int dir = growb >> 13, bb = (growb >> 11) & 3, n = growb & 2047;
        if (gcol < 256) {
          const int h = gcol >> 6, dh = gcol & 63;
#pragma unroll
          for (int r = 0; r < 4; ++r) {
            float q = (acc[rt][ct][r] + bias[gcol]) * SSCALE;
            outb[((size_t)(dir * 16 + bb * 4 + h) * 2048 + (n + r)) * 64 + dh] = f2bf(q);
          }
        } else {
          const int c2 = gcol - 256, h = c2 >> 6, dh = c2 & 63;
          u16x4 pk;
#pragma unroll
          for (int r = 0; r < 4; ++r) pk[r] = f2bf(acc[rt][ct][r] + bias2[c2]);
          *(u16x4*)(outb2 + ((size_t)(dir * 16 + bb * 4 + h) * 64 + dh) * 2048 + n) = pk;
        }
      } else if (EPI == 1) {
#pragma unroll
        for (int r = 0; r < 4; ++r)
          outb[(size_t)(growb + r) * Ncols + gcol] = f2bf(acc[rt][ct][r] + bias[gcol]);
      } else {
#pragma unroll
        for (int r = 0; r < 4; ++r) {
          int grow = growb + r;
          float x = (grow < 8192) ? res0[(size_t)grow * 256 + gcol]
                                  : res1[(size_t)(grow - 8192) * 256 + gcol];
          outf[(size_t)grow * 256 + gcol] = acc[rt][ct][r] + bias[gcol] + x;
        }
      }
    }
  }
}

// ---------------------------------------------------------------------------
// attention v3: 32 problems x 16 q-tiles of 128 rows; 4 waves x 32 q-rows.
// P never touches LDS: K rows are loaded bit-2/3-permuted so the S^T
// (mfma(K,Q)) output fragments redistribute to PV A-fragments with exactly
// two v_permlane32_swap_b32 per (ks,qt) (T12 pattern). Per jt(64 keys):
// 32 MFMA vs 16 KB LDS reads (1/32 B/FLOP). Logits tiny -> softmax without
// max subtraction; normalize in-kernel, write bf16 m_all.
// ---------------------------------------------------------------------------
__global__ __launch_bounds__(256, 2) void k_attn(
    const u16* __restrict__ qk, const u16* __restrict__ vt, u16* __restrict__ m_all)
{
  __shared__ char Kl[2][8192];
  __shared__ char Vl[2][8192];
  const int tid = threadIdx.x, lane = tid & 63, w = tid >> 6;
  const int g = lane >> 4, li = lane & 15;
  const int sw = (blockIdx.x & 7) * 64 + (blockIdx.x >> 3);  // XCD chunking (512=8*64)
  const int qblk = sw & 15;
  const int p = sw >> 4;
  const int dir = p >> 4, bh = p & 15;
  const char* Qg = (const char*)qk + (size_t)p * 262144;
  const char* Kg = (const char*)qk + (size_t)((dir ^ 1) * 16 + bh) * 262144;
  const char* Vg = (const char*)vt + (size_t)((dir ^ 1) * 16 + bh) * 262144;
  const int q0 = qblk * 128 + w * 32;
  const int perm = (li & 3) | ((li & 4) << 1) | ((li & 8) >> 1);  // swap bits 2,3

  // Q fragments in registers (reused across the whole j loop)
  s16x8 qf[2][2];
#pragma unroll
  for (int qt = 0; qt < 2; ++qt)
#pragma unroll
    for (int h = 0; h < 2; ++h)
      qf[qt][h] = *(const s16x8*)(Qg + (size_t)(q0 + qt * 16 + li) * 128 + h * 64 + g * 16);

  auto stageKV = [&](int buf, int jt) {
#pragma unroll
    for (int it = 0; it < 2; ++it) {
      int chunk = it * 256 + w * 64 + lane;
      int row = chunk >> 3, c = chunk & 7;
      int cc = (c ^ (row & 7)) << 4;
      gload_lds16(Kg + (size_t)(jt * 64 + row) * 128 + cc, &Kl[buf][(it * 256 + w * 64) * 16]);
    }
#pragma unroll
    for (int it = 0; it < 2; ++it) {
      int chunk = it * 256 + w * 64 + lane;
      int row = chunk >> 3, c = chunk & 7;
      int cc = (c ^ (row & 7)) << 4;
      gload_lds16(Vg + (size_t)row * 4096 + jt * 128 + cc, &Vl[buf][(it * 256 + w * 64) * 16]);
    }
  };

  f32x4 acco[2][4] = {};
  float accl[2] = {0.f, 0.f};

  stageKV(0, 0);
  __syncthreads();
  for (int jt = 0; jt < 32; ++jt) {
    if (jt + 1 < 32) stageKV((jt + 1) & 1, jt + 1);
    const char* Kb = Kl[jt & 1];
    const char* Vb = Vl[jt & 1];

    // S^T tiles: mfma(K,Q). K rows loaded at perm(li) so lane (g,li) holds
    // keys kt*16 + 8*(g&1) + 4*(g>>1) + r for q-row qt*16+li.
    u32 pw[4][2][2];  // [kt][qt][word]: packed bf16 pairs of exp(S)
#pragma unroll
    for (int kt = 0; kt < 4; ++kt) {
      const int krow = kt * 16 + perm;
      s16x8 kf0 = *(const s16x8*)(Kb + krow * 128 + ((g ^ (krow & 7)) << 4));
      s16x8 kf1 = *(const s16x8*)(Kb + krow * 128 + (((4 + g) ^ (krow & 7)) << 4));
#pragma unroll
      for (int qt = 0; qt < 2; ++qt) {
        f32x4 s = {0.f, 0.f, 0.f, 0.f};
        s = mfma16(kf0, qf[qt][0], s);
        s = mfma16(kf1, qf[qt][1], s);
        float p0 = __expf(s[0]), p1 = __expf(s[1]);
        float p2 = __expf(s[2]), p3 = __expf(s[3]);
        accl[qt] += (p0 + p1) + (p2 + p3);
        pw[kt][qt][0] = (u32)f2bf(p0) | ((u32)f2bf(p1) << 16);
        pw[kt][qt][1] = (u32)f2bf(p2) | ((u32)f2bf(p3) << 16);
      }
    }

    // Build PV A-frags in-register: (word0,word2)=swap(tA.w0,tB.w0), etc.
    s16x8 pf[2][2];  // [ks][qt]
#pragma unroll
    for (int ks = 0; ks < 2; ++ks)
#pragma unroll
      for (int qt = 0; qt < 2; ++qt) {
        u32 a0 = pw[ks * 2][qt][0], b0 = pw[ks * 2 + 1][qt][0];
        u32 a1 = pw[ks * 2][qt][1], b1 = pw[ks * 2 + 1][qt][1];
        asm("v_permlane32_swap_b32 %0, %1" : "+v"(a0), "+v"(b0));
        asm("v_permlane32_swap_b32 %0, %1" : "+v"(a1), "+v"(b1));
        u32 words[4] = {a0, a1, b0, b1};
        __builtin_memcpy(&pf[ks][qt], words, 16);
      }

    // O += P V
#pragma unroll
    for (int ks = 0; ks < 2; ++ks)
#pragma unroll
      for (int dt = 0; dt < 4; ++dt) {
        const int vrow = dt * 16 + li;
        s16x8 vfr = *(const s16x8*)(Vb + vrow * 128 + (((ks * 4 + g) ^ (vrow & 7)) << 4));
        acco[0][dt] = mfma16(pf[ks][0], vfr, acco[0][dt]);
        acco[1][dt] = mfma16(pf[ks][1], vfr, acco[1][dt]);
      }
    __syncthreads();
  }

  // row sums: accl[qt] is partial for q-row qt*16+li; reduce across g-groups.
  float invq[2][4];
#pragma unroll
  for (int qt = 0; qt < 2; ++qt) {
    float v = accl[qt];
    v += __shfl_xor(v, 16);
    v += __shfl_xor(v, 32);
    float inv = 1.0f / v;
#pragma unroll
    for (int r = 0; r < 4; ++r) invq[qt][r] = __shfl(inv, g * 4 + r);
  }

  const int bb = bh >> 2, h = bh & 3;
#pragma unroll
  for (int qt = 0; qt < 2; ++qt) {
    const size_t rowb = (size_t)dir * 8192 + (size_t)bb * 2048 + q0 + qt * 16 + g * 4;
#pragma unroll
    for (int dt = 0; dt < 4; ++dt)
#pragma unroll
      for (int r = 0; r < 4; ++r)
        m_all[(rowb + r) * 256 + h * 64 + dt * 16 + li] = f2bf(acco[qt][dt][r] * invq[qt][r]);
  }
}

// ---------------------------------------------------------------------------
// layernorm (over 512) + exact gelu; one wave per row
// ---------------------------------------------------------------------------
__global__ __launch_bounds__(256) void k_ln_gelu(
    const u16* __restrict__ h, const float* __restrict__ lg,
    const float* __restrict__ lb, u16* __restrict__ o)
{
  int lane = threadIdx.x & 63;
  size_t row = blockIdx.x * 4 + (threadIdx.x >> 6);
  s16x8 v = *(const s16x8*)(h + row * 512 + lane * 8);
  float f[8], s = 0.f, s2 = 0.f;
#pragma unroll
  for (int j = 0; j < 8; ++j) { f[j] = bf2f((u16)v[j]); s += f[j]; s2 += f[j] * f[j]; }
#pragma unroll
  for (int m = 1; m < 64; m <<= 1) { s += __shfl_xor(s, m); s2 += __shfl_xor(s2, m); }
  float mu = s * (1.0f / 512.0f);
  float var = s2 * (1.0f / 512.0f) - mu * mu;
  float rs = rsqrtf(var + 1e-5f);
  s16x8 ov;
#pragma unroll
  for (int j = 0; j < 8; ++j) {
    int c = lane * 8 + j;
    float y = (f[j] - mu) * rs * lg[c] + lb[c];
    float ge = 0.5f * y * (1.0f + erff(y * 0.70710678118654752f));
    ov[j] = (short)f2bf(ge);
  }
  *(s16x8*)(o + row * 512 + lane * 8) = ov;
}

// ---------------------------------------------------------------------------
extern "C" void kernel_launch(void* const* d_in, const int* in_sizes, int n_in,
                              void* d_out, int out_size, void* d_ws, size_t ws_size,
                              hipStream_t stream)
{
  const float* x0  = (const float*)d_in[0];
  const float* x1  = (const float*)d_in[1];
  const float* Wqk = (const float*)d_in[2];
  const float* bqk = (const float*)d_in[3];
  const float* Wv  = (const float*)d_in[4];
  const float* bv  = (const float*)d_in[5];
  const float* Wo  = (const float*)d_in[6];
  const float* bo  = (const float*)d_in[7];
  const float* W1  = (const float*)d_in[8];
  const float* b1  = (const float*)d_in[9];
  const float* lg  = (const float*)d_in[10];
  const float* lb  = (const float*)d_in[11];
  const float* W2  = (const float*)d_in[12];
  const float* b2  = (const float*)d_in[13];
  float* out = (float*)d_out;
  char* ws = (char*)d_ws;

  u16*   Xb    = (u16*)(ws + 0);          // 16384x256 bf16
  u16*   qk    = (u16*)(ws + 8388608);    // [2][4][4][2048][64] bf16 (scaled)
  u16*   vt    = (u16*)(ws + 16777216);   // [2][4][4][64][2048] bf16 (V^T)
  u16*   m_all = (u16*)(ws + 25165824);   // 16384x256 bf16 (normalized attn out)
  u16*   hpre  = (u16*)(ws + 33554432);   // 16384x512 bf16
  u16*   gact  = (u16*)(ws + 50331648);   // 16384x512 bf16
  u16*   btqkv = (u16*)(ws + 67108864);   // [512][256]
  u16*   btF   = (u16*)(ws + 67371008);   // [512][512]: [:, :256]=W1a^T, [:, 256:]=Wc^T
  u16*   bt2   = (u16*)(ws + 67895296);   // [256][512]
  float* bc    = (float*)(ws + 68419584); // [512] fused FFN1 bias

  k_prep<<<dim3(2658), dim3(256), 0, stream>>>(x0, x1, Wqk, Wv, Wo, W1, W2, bo, b1,
                                               btqkv, btF, bt2, bc, Xb);
  k_gemm<256, 256, 0, 128><<<dim3(128, 4), dim3(256), 0, stream>>>(
      Xb, nullptr, btqkv, bqk, bv, nullptr, nullptr, qk, vt, nullptr, 512);
  k_attn<<<dim3(512), dim3(256), 0, stream>>>(qk, vt, m_all);
  k_gemm<512, 256, 1, 128><<<dim3(128, 4), dim3(256), 0, stream>>>(
      Xb, m_all, btF, bc, nullptr, nullptr, nullptr, hpre, nullptr, nullptr, 512);
  k_ln_gelu<<<dim3(4096), dim3(256), 0, stream>>>(hpre, lg, lb, gact);
  k_gemm<512, 512, 3, 64><<<dim3(128, 4), dim3(256), 0, stream>>>(
      gact, nullptr, bt2, b2, nullptr, x0, x1, nullptr, nullptr, out, 256);
}

// Round 5
// 223.408 us; speedup vs baseline: 1.0658x; 1.0314x over previous
//
#include <hip/hip_runtime.h>
#include <hip/hip_bf16.h>
#include <math.h>

#define DEV static __device__ __forceinline__

typedef float f32x4 __attribute__((ext_vector_type(4)));
typedef short s16x8 __attribute__((ext_vector_type(8)));
typedef unsigned short u16;
typedef unsigned int u32;
typedef u32 u32x2 __attribute__((ext_vector_type(2)));
typedef u16 u16x4 __attribute__((ext_vector_type(4)));
typedef u16 u16x8 __attribute__((ext_vector_type(8)));

#define SSCALE 0.35355339059327379f   // 64^-0.25
// SSCALE * sqrt(log2(e)): folds the exp->exp2 conversion into the symmetric
// qk scaling (s*log2e = (q*c)(k*c) with c^2 = log2e), so softmax uses raw
// v_exp_f32 with no per-element multiply.
#define SS2 0.42466089345200966f

DEV f32x4 mfma16(s16x8 a, s16x8 b, f32x4 c) {
  return __builtin_amdgcn_mfma_f32_16x16x32_bf16(a, b, c, 0, 0, 0);
}

DEV float bf2f(u16 x) { u32 u = ((u32)x) << 16; float f; __builtin_memcpy(&f, &u, 4); return f; }
DEV u16 f2bf(float x) { __hip_bfloat16 b = __float2bfloat16(x); u16 r; __builtin_memcpy(&r, &b, 2); return r; }

DEV float fexp2(float x) {
#if __has_builtin(__builtin_amdgcn_exp2f)
  return __builtin_amdgcn_exp2f(x);
#else
  return exp2f(x);
#endif
}

DEV void gload_lds16(const void* g, void* l) {
  __builtin_amdgcn_global_load_lds((const __attribute__((address_space(1))) u32*)g,
                                   (__attribute__((address_space(3))) u32*)l, 16, 0, 0);
}

// ---------------------------------------------------------------------------
// prep (multi-mode by block range):
//   [0,2048)    x0|x1 -> Xb bf16 (vectorized)
//   [2048,2144) 96 LDS-tiled 64x64 transposes: Wqk^T,Wv^T -> btqkv;
//               W1a^T -> btF[:, :256]; W2^T -> bt2
//   [2144,2656) Wc = Wo @ W1b (f32 accum) -> btF[:, 256:]   (Wo-GEMM fusion)
//   [2656,2658) bc = b1 + bo @ W1b (f32)
// ---------------------------------------------------------------------------
__global__ __launch_bounds__(256) void k_prep(
    const float* __restrict__ x0, const float* __restrict__ x1,
    const float* __restrict__ Wqk, const float* __restrict__ Wv,
    const float* __restrict__ Wo, const float* __restrict__ W1,
    const float* __restrict__ W2, const float* __restrict__ bo,
    const float* __restrict__ b1,
    u16* __restrict__ btqkv, u16* __restrict__ btF,
    u16* __restrict__ bt2, float* __restrict__ bc, u16* __restrict__ Xb)
{
  const int blk = blockIdx.x, tid = threadIdx.x;
  if (blk < 2048) {               // x convert: 2048 elems per block
    int idx = blk * 2048 + tid * 8;
    const float* src = (idx < 2097152) ? (x0 + idx) : (x1 + (idx - 2097152));
    f32x4 va = *(const f32x4*)src;
    f32x4 vb = *(const f32x4*)(src + 4);
    u16x8 o;
#pragma unroll
    for (int j = 0; j < 4; ++j) { o[j] = f2bf(va[j]); o[4 + j] = f2bf(vb[j]); }
    *(u16x8*)(Xb + idx) = o;
  } else if (blk < 2144) {        // transpose tiles
    __shared__ float T[64][65];
    int tb = blk - 2048;
    const float* src; u16* dst; int sld, dld, kr0, c0, drow0;
    if (tb < 16)      { src = Wqk; dst = btqkv; sld = 256; dld = 256; drow0 = 0;
                        kr0 = (tb >> 2) * 64; c0 = (tb & 3) * 64; }
    else if (tb < 32) { tb -= 16; src = Wv; dst = btqkv; sld = 256; dld = 256; drow0 = 256;
                        kr0 = (tb >> 2) * 64; c0 = (tb & 3) * 64; }
    else if (tb < 64) { tb -= 32; src = W1; dst = btF; sld = 512; dld = 512; drow0 = 0;
                        kr0 = (tb >> 3) * 64; c0 = (tb & 7) * 64; }
    else              { tb -= 64; src = W2; dst = bt2; sld = 256; dld = 512; drow0 = 0;
                        kr0 = (tb >> 2) * 64; c0 = (tb & 3) * 64; }
    int r = tid >> 2, cq = (tid & 3) * 16;
#pragma unroll
    for (int q = 0; q < 4; ++q) {
      f32x4 v = *(const f32x4*)(src + (size_t)(kr0 + r) * sld + c0 + cq + q * 4);
#pragma unroll
      for (int e = 0; e < 4; ++e) T[r][cq + q * 4 + e] = v[e];
    }
    __syncthreads();
    int c = tid >> 2, kq = (tid & 3) * 16;
#pragma unroll
    for (int q = 0; q < 2; ++q) {
      u16x8 o;
#pragma unroll
      for (int e = 0; e < 8; ++e) o[e] = f2bf(T[kq + q * 8 + e][c]);
      *(u16x8*)(dst + (size_t)(drow0 + c0 + c) * dld + kr0 + kq + q * 8) = o;
    }
  } else if (blk < 2656) {        // Wc^T[n][i] = sum_j W1[(256+j)][n] * Wo[i][j]
    int wb = blk - 2144;
    int i = wb >> 1;
    int n = (wb & 1) * 256 + tid;
    float a0 = 0.f, a1 = 0.f, a2 = 0.f, a3 = 0.f;
    for (int j = 0; j < 256; j += 4) {
      a0 = fmaf(Wo[i * 256 + j],     W1[(size_t)(256 + j) * 512 + n], a0);
      a1 = fmaf(Wo[i * 256 + j + 1], W1[(size_t)(257 + j) * 512 + n], a1);
      a2 = fmaf(Wo[i * 256 + j + 2], W1[(size_t)(258 + j) * 512 + n], a2);
      a3 = fmaf(Wo[i * 256 + j + 3], W1[(size_t)(259 + j) * 512 + n], a3);
    }
    btF[(size_t)n * 512 + 256 + i] = f2bf((a0 + a1) + (a2 + a3));
  } else {                        // bc[n] = b1[n] + sum_j bo[j]*W1[(256+j)][n]
    int n = (blk - 2656) * 256 + tid;
    float acc = b1[n];
    for (int j = 0; j < 256; ++j)
      acc = fmaf(bo[j], W1[(size_t)(256 + j) * 512 + n], acc);
    bc[n] = acc;
  }
}

// ---------------------------------------------------------------------------
// GEMM: C[16384 x Ncols] = A(bf16,[M][KD], split A1|A2 at K1) @ Bt^T
// Bt is [Ncols][KD] bf16. 128xBN tile, 4 waves, BK=32, double-buffered
// global_load_lds, XOR-swizzled LDS.
// EPI 0: qk/vt scatter (+bias,*SS2 / +bias, packed-n stores)
// EPI 1: bf16 out (+bias)      EPI 3: f32 out (+bias +residual x)
// ---------------------------------------------------------------------------
template <int KD, int K1, int EPI, int BN>
__global__ __launch_bounds__(256, 2) void k_gemm(
    const u16* __restrict__ A1, const u16* __restrict__ A2,
    const u16* __restrict__ Bt,
    const float* __restrict__ bias, const float* __restrict__ bias2,
    const float* __restrict__ res0, const float* __restrict__ res1,
    u16* __restrict__ outb, u16* __restrict__ outb2,
    float* __restrict__ outf, int Ncols)
{
  constexpr int MR = (BN == 128) ? 4 : 2;       // row-tiles per wave
  __shared__ char lds[16384 + 2 * BN * 64];
  char* ldsA = lds;
  char* ldsB = lds + 16384;
  const int tid = threadIdx.x;
  const int lane = tid & 63;
  const int w = tid >> 6;
  const int wm = (BN == 128) ? (w >> 1) : w;
  const int wn = (BN == 128) ? (w & 1) : 0;
  const int g = lane >> 4, li = lane & 15;
  const int m0 = blockIdx.x * 128, n0 = blockIdx.y * BN;

  auto stage = [&](int buf, int t) {
    const int k0 = t * 32;
#pragma unroll
    for (int it = 0; it < 2; ++it) {
      int chunk = it * 256 + w * 64 + lane;
      int row = chunk >> 2, c = chunk & 3;
      int kc = k0 + ((c ^ ((row >> 1) & 3)) << 3);
      const u16* src = (kc < K1) ? (A1 + (size_t)(m0 + row) * K1 + kc)
                                 : (A2 + (size_t)(m0 + row) * (KD - K1) + (kc - K1));
      gload_lds16(src, ldsA + buf * 8192 + (it * 256 + w * 64) * 16);
    }
#pragma unroll
    for (int it = 0; it < BN / 64; ++it) {
      int chunk = it * 256 + w * 64 + lane;
      int row = chunk >> 2, c = chunk & 3;
      int kc = k0 + ((c ^ ((row >> 1) & 3)) << 3);
      gload_lds16(Bt + (size_t)(n0 + row) * KD + kc,
                  ldsB + buf * (BN * 64) + (it * 256 + w * 64) * 16);
    }
  };

  f32x4 acc[MR][4] = {};

  stage(0, 0);
  __syncthreads();
  const int NT = KD / 32;
  for (int t = 0; t < NT; ++t) {
    if (t + 1 < NT) stage((t + 1) & 1, t + 1);
    const char* bufA = ldsA + (t & 1) * 8192;
    const char* bufB = ldsB + (t & 1) * (BN * 64);
    s16x8 af[MR], bfr[4];
#pragma unroll
    for (int rt = 0; rt < MR; ++rt) {
      int row = wm * (MR * 16) + rt * 16 + li;
      af[rt] = *(const s16x8*)(bufA + row * 64 + ((g ^ ((row >> 1) & 3)) << 4));
    }
#pragma unroll
    for (int ct = 0; ct < 4; ++ct) {
      int col = wn * 64 + ct * 16 + li;
      bfr[ct] = *(const s16x8*)(bufB + col * 64 + ((g ^ ((col >> 1) & 3)) << 4));
    }
#pragma unroll
    for (int rt = 0; rt < MR; ++rt)
#pragma unroll
      for (int ct = 0; ct < 4; ++ct)
        acc[rt][ct] = mfma16(af[rt], bfr[ct], acc[rt][ct]);
    __syncthreads();
  }

#pragma unroll
  for (int rt = 0; rt < MR; ++rt) {
#pragma unroll
    for (int ct = 0; ct < 4; ++ct) {
      const int growb = m0 + wm * (MR * 16) + rt * 16 + g * 4;   // base row (r=0)
      const int gcol = n0 + wn * 64 + ct * 16 + li;
      if (EPI == 0) {
        const int dir = growb >> 13, bb = (growb >> 11) & 3, n = growb & 2047;
        if (gcol < 256) {
          const int h = gcol >> 6, dh = gcol & 63;
#pragma unroll
          for (int r = 0; r < 4; ++r) {
            float q = (acc[rt][ct][r] + bias[gcol]) * SS2;
            outb[((size_t)(dir * 16 + bb * 4 + h) * 2048 + (n + r)) * 64 + dh] = f2bf(q);
          }
        } else {
          const int c2 = gcol - 256, h = c2 >> 6, dh = c2 & 63;
          u16x4 pk;
#pragma unroll
          for (int r = 0; r < 4; ++r) pk[r] = f2bf(acc[rt][ct][r] + bias2[c2]);
          *(u16x4*)(outb2 + ((size_t)(dir * 16 + bb * 4 + h) * 64 + dh) * 2048 + n) = pk;
        }
      } else if (EPI == 1) {
#pragma unroll
        for (int r = 0; r < 4; ++r)
          outb[(size_t)(growb + r) * Ncols + gcol] = f2bf(acc[rt][ct][r] + bias[gcol]);
      } else {
#pragma unroll
        for (int r = 0; r < 4; ++r) {
          int grow = growb + r;
          float x = (grow < 8192) ? res0[(size_t)grow * 256 + gcol]
                                  : res1[(size_t)(grow - 8192) * 256 + gcol];
          outf[(size_t)grow * 256 + gcol] = acc[rt][ct][r] + bias[gcol] + x;
        }
      }
    }
  }
}

// ---------------------------------------------------------------------------
// attention v4: in-block split-KV. 512 threads = 8 waves; waves 0-3 process
// keys [0,1024), waves 4-7 keys [1024,2048) for the same 128 q-rows
// (32 rows/wave). Doubles waves/SIMD (2->4) to hide the serial
// QK->exp->permlane->PV chain; halves barrier count. Partials combined
// in-block through the freed K-LDS (no global round trip).
// P never touches LDS (permlane32_swap redistribution, T12).
// Logits pre-scaled by sqrt(log2 e) -> softmax is raw v_exp_f32.
// ---------------------------------------------------------------------------
__global__ __launch_bounds__(512, 4) void k_attn(
    const u16* __restrict__ qk, const u16* __restrict__ vt, u16* __restrict__ m_all)
{
  __shared__ char Kl[2][2][8192];   // [half][buf]
  __shared__ char Vl[2][2][8192];
  const int tid = threadIdx.x, lane = tid & 63, w = tid >> 6;
  const int half = w >> 2, wq = w & 3;
  const int g = lane >> 4, li = lane & 15;
  const int sw = (blockIdx.x & 7) * 64 + (blockIdx.x >> 3);  // XCD chunking (512=8*64)
  const int qblk = sw & 15;
  const int p = sw >> 4;
  const int dir = p >> 4, bh = p & 15;
  const char* Qg = (const char*)qk + (size_t)p * 262144;
  const char* Kg = (const char*)qk + (size_t)((dir ^ 1) * 16 + bh) * 262144;
  const char* Vg = (const char*)vt + (size_t)((dir ^ 1) * 16 + bh) * 262144;
  const int q0 = qblk * 128 + wq * 32;
  const int perm = (li & 3) | ((li & 4) << 1) | ((li & 8) >> 1);  // swap bits 2,3

  // Q fragments in registers (reused across the whole j loop)
  s16x8 qf[2][2];
#pragma unroll
  for (int qt = 0; qt < 2; ++qt)
#pragma unroll
    for (int h = 0; h < 2; ++h)
      qf[qt][h] = *(const s16x8*)(Qg + (size_t)(q0 + qt * 16 + li) * 128 + h * 64 + g * 16);

  auto stageKV = [&](int buf, int jt) {
    const int kb = half * 1024 + jt * 64;    // key base for this half
#pragma unroll
    for (int it = 0; it < 2; ++it) {
      int chunk = it * 256 + wq * 64 + lane;
      int row = chunk >> 3, c = chunk & 7;
      int cc = (c ^ (row & 7)) << 4;
      gload_lds16(Kg + (size_t)(kb + row) * 128 + cc, &Kl[half][buf][chunk * 16]);
    }
#pragma unroll
    for (int it = 0; it < 2; ++it) {
      int chunk = it * 256 + wq * 64 + lane;
      int row = chunk >> 3, c = chunk & 7;
      int cc = (c ^ (row & 7)) << 4;
      gload_lds16(Vg + (size_t)row * 4096 + kb * 2 + cc, &Vl[half][buf][chunk * 16]);
    }
  };

  f32x4 acco[2][4] = {};
  float accl[2] = {0.f, 0.f};

  stageKV(0, 0);
  __syncthreads();
  for (int jt = 0; jt < 16; ++jt) {
    if (jt + 1 < 16) stageKV((jt + 1) & 1, jt + 1);
    const char* Kb = &Kl[half][jt & 1][0];
    const char* Vb = &Vl[half][jt & 1][0];

    // S^T tiles: mfma(K,Q). K rows loaded at perm(li) so lane (g,li) holds
    // keys kt*16 + 8*(g&1) + 4*(g>>1) + r for q-row qt*16+li.
    u32 pw[4][2][2];  // [kt][qt][word]: packed bf16 pairs of exp2(S')
#pragma unroll
    for (int kt = 0; kt < 4; ++kt) {
      const int krow = kt * 16 + perm;
      s16x8 kf0 = *(const s16x8*)(Kb + krow * 128 + ((g ^ (krow & 7)) << 4));
      s16x8 kf1 = *(const s16x8*)(Kb + krow * 128 + (((4 + g) ^ (krow & 7)) << 4));
#pragma unroll
      for (int qt = 0; qt < 2; ++qt) {
        f32x4 s = {0.f, 0.f, 0.f, 0.f};
        s = mfma16(kf0, qf[qt][0], s);
        s = mfma16(kf1, qf[qt][1], s);
        float p0 = fexp2(s[0]), p1 = fexp2(s[1]);
        float p2 = fexp2(s[2]), p3 = fexp2(s[3]);
        accl[qt] += (p0 + p1) + (p2 + p3);
        pw[kt][qt][0] = (u32)f2bf(p0) | ((u32)f2bf(p1) << 16);
        pw[kt][qt][1] = (u32)f2bf(p2) | ((u32)f2bf(p3) << 16);
      }
    }

    // Build PV A-frags in-register: two permlane32_swap per (ks,qt).
    s16x8 pf[2][2];  // [ks][qt]
#pragma unroll
    for (int ks = 0; ks < 2; ++ks)
#pragma unroll
      for (int qt = 0; qt < 2; ++qt) {
        u32 a0 = pw[ks * 2][qt][0], b0 = pw[ks * 2 + 1][qt][0];
        u32 a1 = pw[ks * 2][qt][1], b1 = pw[ks * 2 + 1][qt][1];
        asm("v_permlane32_swap_b32 %0, %1" : "+v"(a0), "+v"(b0));
        asm("v_permlane32_swap_b32 %0, %1" : "+v"(a1), "+v"(b1));
        u32 words[4] = {a0, a1, b0, b1};
        __builtin_memcpy(&pf[ks][qt], words, 16);
      }

    // O += P V
#pragma unroll
    for (int ks = 0; ks < 2; ++ks)
#pragma unroll
      for (int dt = 0; dt < 4; ++dt) {
        const int vrow = dt * 16 + li;
        s16x8 vfr = *(const s16x8*)(Vb + vrow * 128 + (((ks * 4 + g) ^ (vrow & 7)) << 4));
        acco[0][dt] = mfma16(pf[ks][0], vfr, acco[0][dt]);
        acco[1][dt] = mfma16(pf[ks][1], vfr, acco[1][dt]);
      }
    __syncthreads();
  }

  // reduce row sums across g-groups (replicated to all lanes per li)
#pragma unroll
  for (int qt = 0; qt < 2; ++qt) {
    float v = accl[qt];
    v += __shfl_xor(v, 16);
    v += __shfl_xor(v, 32);
    accl[qt] = v;
  }

  // in-block half-combine through freed LDS (K region = 32KB O scratch,
  // V region = l scratch). All waves are synced at loop exit.
  float* scr  = (float*)&Kl[0][0][0];
  float* lscr = (float*)&Vl[0][0][0];
  if (half == 0) {
#pragma unroll
    for (int qt = 0; qt < 2; ++qt)
#pragma unroll
      for (int dt = 0; dt < 4; ++dt)
        *(f32x4*)(scr + wq * 2048 + lane * 32 + (((qt * 4 + dt) * 4) ^ ((lane & 7) << 2))) =
            acco[qt][dt];
    if (lane < 16) {
      lscr[wq * 32 + li] = accl[0];
      lscr[wq * 32 + 16 + li] = accl[1];
    }
  }
  __syncthreads();
  if (half == 1) {
    float invq[2][4];
#pragma unroll
    for (int qt = 0; qt < 2; ++qt) {
      float ltot = accl[qt] + lscr[wq * 32 + qt * 16 + li];
      float inv = 1.0f / ltot;
#pragma unroll
      for (int r = 0; r < 4; ++r) invq[qt][r] = __shfl(inv, g * 4 + r);
    }
    const int bb = bh >> 2, h = bh & 3;
#pragma unroll
    for (int qt = 0; qt < 2; ++qt) {
      const size_t rowb = (size_t)dir * 8192 + (size_t)bb * 2048 + q0 + qt * 16 + g * 4;
#pragma unroll
      for (int dt = 0; dt < 4; ++dt) {
        f32x4 o = *(const f32x4*)(scr + wq * 2048 + lane * 32 +
                                  (((qt * 4 + dt) * 4) ^ ((lane & 7) << 2)));
#pragma unroll
        for (int r = 0; r < 4; ++r)
          m_all[(rowb + r) * 256 + h * 64 + dt * 16 + li] =
              f2bf((acco[qt][dt][r] + o[r]) * invq[qt][r]);
      }
    }
  }
}

// ---------------------------------------------------------------------------
// layernorm (over 512) + exact gelu; one wave per row
// ---------------------------------------------------------------------------
__global__ __launch_bounds__(256) void k_ln_gelu(
    const u16* __restrict__ h, const float* __restrict__ lg,
    const float* __restrict__ lb, u16* __restrict__ o)
{
  int lane = threadIdx.x & 63;
  size_t row = blockIdx.x * 4 + (threadIdx.x >> 6);
  s16x8 v = *(const s16x8*)(h + row * 512 + lane * 8);
  float f[8], s = 0.f, s2 = 0.f;
#pragma unroll
  for (int j = 0; j < 8; ++j) { f[j] = bf2f((u16)v[j]); s += f[j]; s2 += f[j] * f[j]; }
#pragma unroll
  for (int m = 1; m < 64; m <<= 1) { s += __shfl_xor(s, m); s2 += __shfl_xor(s2, m); }
  float mu = s * (1.0f / 512.0f);
  float var = s2 * (1.0f / 512.0f) - mu * mu;
  float rs = rsqrtf(var + 1e-5f);
  s16x8 ov;
#pragma unroll
  for (int j = 0; j < 8; ++j) {
    int c = lane * 8 + j;
    float y = (f[j] - mu) * rs * lg[c] + lb[c];
    float ge = 0.5f * y * (1.0f + erff(y * 0.70710678118654752f));
    ov[j] = (short)f2bf(ge);
  }
  *(s16x8*)(o + row * 512 + lane * 8) = ov;
}

// ---------------------------------------------------------------------------
extern "C" void kernel_launch(void* const* d_in, const int* in_sizes, int n_in,
                              void* d_out, int out_size, void* d_ws, size_t ws_size,
                              hipStream_t stream)
{
  const float* x0  = (const float*)d_in[0];
  const float* x1  = (const float*)d_in[1];
  const float* Wqk = (const float*)d_in[2];
  const float* bqk = (const float*)d_in[3];
  const float* Wv  = (const float*)d_in[4];
  const float* bv  = (const float*)d_in[5];
  const float* Wo  = (const float*)d_in[6];
  const float* bo  = (const float*)d_in[7];
  const float* W1  = (const float*)d_in[8];
  const float* b1  = (const float*)d_in[9];
  const float* lg  = (const float*)d_in[10];
  const float* lb  = (const float*)d_in[11];
  const float* W2  = (const float*)d_in[12];
  const float* b2  = (const float*)d_in[13];
  float* out = (float*)d_out;
  char* ws = (char*)d_ws;

  u16*   Xb    = (u16*)(ws + 0);          // 16384x256 bf16
  u16*   qk    = (u16*)(ws + 8388608);    // [2][4][4][2048][64] bf16 (scaled)
  u16*   vt    = (u16*)(ws + 16777216);   // [2][4][4][64][2048] bf16 (V^T)
  u16*   m_all = (u16*)(ws + 25165824);   // 16384x256 bf16 (normalized attn out)
  u16*   hpre  = (u16*)(ws + 33554432);   // 16384x512 bf16
  u16*   gact  = (u16*)(ws + 50331648);   // 16384x512 bf16
  u16*   btqkv = (u16*)(ws + 67108864);   // [512][256]
  u16*   btF   = (u16*)(ws + 67371008);   // [512][512]: [:, :256]=W1a^T, [:, 256:]=Wc^T
  u16*   bt2   = (u16*)(ws + 67895296);   // [256][512]
  float* bc    = (float*)(ws + 68419584); // [512] fused FFN1 bias

  k_prep<<<dim3(2658), dim3(256), 0, stream>>>(x0, x1, Wqk, Wv, Wo, W1, W2, bo, b1,
                                               btqkv, btF, bt2, bc, Xb);
  k_gemm<256, 256, 0, 128><<<dim3(128, 4), dim3(256), 0, stream>>>(
      Xb, nullptr, btqkv, bqk, bv, nullptr, nullptr, qk, vt, nullptr, 512);
  k_attn<<<dim3(512), dim3(512), 0, stream>>>(qk, vt, m_all);
  k_gemm<512, 256, 1, 128><<<dim3(128, 4), dim3(256), 0, stream>>>(
      Xb, m_all, btF, bc, nullptr, nullptr, nullptr, hpre, nullptr, nullptr, 512);
  k_ln_gelu<<<dim3(4096), dim3(256), 0, stream>>>(hpre, lg, lb, gact);
  k_gemm<512, 512, 3, 64><<<dim3(128, 4), dim3(256), 0, stream>>>(
      gact, nullptr, bt2, b2, nullptr, x0, x1, nullptr, nullptr, out, 256);
}